// Round 10
// baseline (412.776 us; speedup 1.0000x reference)
//
#include <hip/hip_runtime.h>
#include <hip/hip_bf16.h>
#include <stdint.h>

#define NL 2048
#define NR 4096
#define NCHUNK 8
#define CHUNK (NR / NCHUNK) /* 512 */
#define SCALE 0.125f
#define LN_EPS 1e-5f

typedef __attribute__((ext_vector_type(8))) short short8;  // 8 bf16 in 4 VGPRs
typedef __attribute__((ext_vector_type(4))) float float4v;

static __device__ __forceinline__ short f2bf(float f) {
  union { float f; uint32_t u; } v; v.f = f;
  uint32_t u = v.u;
  uint32_t r = (u + 0x7FFFu + ((u >> 16) & 1u)) >> 16;  // RNE
  return (short)(r & 0xFFFFu);
}
static __device__ __forceinline__ float bf2f(short b) {
  union { uint32_t u; float f; } v; v.u = ((uint32_t)(uint16_t)b) << 16;
  return v.f;
}
// packed f32x2 -> bf16x2 (RNE), lo = a, hi = b
static __device__ __forceinline__ uint32_t cvtpk(float a, float b) {
  uint32_t r;
  asm("v_cvt_pk_bf16_f32 %0, %1, %2" : "=v"(r) : "v"(a), "v"(b));
  return r;
}

// ---------------- K0: fp32 -> bf16 conversions -------------------------------
__global__ void k0_cvt(const float* __restrict__ q, const float* __restrict__ kv,
                       const float* __restrict__ Wq, const float* __restrict__ Wk,
                       const float* __restrict__ Wv, const float* __restrict__ Wo,
                       short* __restrict__ qb, short* __restrict__ kvb,
                       short* __restrict__ Wqb, short* __restrict__ Wkb,
                       short* __restrict__ Wvb, short* __restrict__ Wob) {
  int i = blockIdx.x * blockDim.x + threadIdx.x;
  const float* src; short* dst;
  if (i < 131072)                 { src = q;  dst = qb;  }
  else if ((i -= 131072) < 262144){ src = kv; dst = kvb; }
  else if ((i -= 262144) < 32768) { src = Wq; dst = Wqb; }
  else if ((i -= 32768) < 32768)  { src = Wk; dst = Wkb; }
  else if ((i -= 32768) < 32768)  { src = Wv; dst = Wvb; }
  else { i -= 32768;                src = Wo; dst = Wob; }
  const float4* s4 = reinterpret_cast<const float4*>(src) + (size_t)i * 2;
  float4 a = s4[0], b = s4[1];
  short8 o;
  o[0] = f2bf(a.x); o[1] = f2bf(a.y); o[2] = f2bf(a.z); o[3] = f2bf(a.w);
  o[4] = f2bf(b.x); o[5] = f2bf(b.y); o[6] = f2bf(b.z); o[7] = f2bf(b.w);
  *reinterpret_cast<short8*>(dst + (size_t)i * 8) = o;
}

// ---------------- K1: projections (X @ W^T) as bf16 MFMA ---------------------
__global__ void k1_proj(const short* __restrict__ qb, const short* __restrict__ kvb,
                        const short* __restrict__ Wqb, const short* __restrict__ Wkb,
                        const short* __restrict__ Wvb,
                        short* __restrict__ Qb, short* __restrict__ Kb,
                        short* __restrict__ VT) {
  int lane = threadIdx.x & 63, warp = threadIdx.x >> 6;
  int wid = blockIdx.x * 4 + warp;
  int lr = lane & 15, lg = lane >> 4;
  const short *src, *W; short* dst; int mt, ct, mode;
  if (wid < 1024)      { src = qb;  W = Wqb; dst = Qb; mt = wid & 127; ct = wid >> 7; mode = 0; }
  else if (wid < 3072) { int id = wid - 1024; src = kvb; W = Wkb; dst = Kb; mt = id & 255; ct = id >> 8; mode = 0; }
  else                 { int id = wid - 3072; src = kvb; W = Wvb; dst = VT; mt = id & 255; ct = id >> 8; mode = 1; }
  int m0 = mt * 16, c0 = ct * 64;
  float4v acc[4] = {};
  const short* arow = src + (m0 + lr) * 512 + 8 * lg;
#pragma unroll
  for (int kk = 0; kk < 16; ++kk) {
    short8 a = *reinterpret_cast<const short8*>(arow + kk * 32);
#pragma unroll
    for (int cs = 0; cs < 4; ++cs) {
      const short* bp = W + (c0 + cs * 16 + lr) * 512 + kk * 32 + 8 * lg;
      short8 b = *reinterpret_cast<const short8*>(bp);
      acc[cs] = __builtin_amdgcn_mfma_f32_16x16x32_bf16(a, b, acc[cs], 0, 0, 0);
    }
  }
  if (mode == 0) {
#pragma unroll
    for (int cs = 0; cs < 4; ++cs)
#pragma unroll
      for (int j = 0; j < 4; ++j)
        dst[(m0 + 4 * lg + j) * 512 + c0 + cs * 16 + lr] = f2bf(acc[cs][j]);
  } else {
#pragma unroll
    for (int cs = 0; cs < 4; ++cs)
#pragma unroll
      for (int j = 0; j < 4; ++j)
        dst[(c0 + cs * 16 + lr) * 4096 + m0 + 4 * lg + j] = f2bf(acc[cs][j]);
  }
}

// ----- shared prefetch macro: K-fragments for iteration itv into K0..K3 ------
#define PREFK(K0, K1, K2, K3, itv)                                            \
  {                                                                           \
    int r0p = r_base + (itv) * 32;                                            \
    const short* kp0 = Kb + (size_t)(r0p + lr) * 512 + w * 64 + 8 * lg;       \
    K0 = *reinterpret_cast<const short8*>(kp0);                               \
    K1 = *reinterpret_cast<const short8*>(kp0 + 32);                          \
    const short* kp1 = kp0 + 16 * 512;                                        \
    K2 = *reinterpret_cast<const short8*>(kp1);                               \
    K3 = *reinterpret_cast<const short8*>(kp1 + 32);                          \
  }

// ---------------- K2: pass A — per-(head,row) sum of exp(logit) --------------
// Swapped QK. Explicit K double-buffer (A/B register sets, 2x-unrolled loop);
// bias float4 issued at body top. No LDS, no barriers.
#define K2_BODY(itv, KC0, KC1, KC2, KC3, KN0, KN1, KN2, KN3, PREF)            \
  {                                                                           \
    int r0 = r_base + (itv) * 32;                                             \
    const float* bp = bias + (size_t)(l0 + lr) * NR + r0 + 4 * lg;            \
    float4 bv0 = *reinterpret_cast<const float4*>(bp);                        \
    float4 bv1 = *reinterpret_cast<const float4*>(bp + 16);                   \
    if (PREF) PREFK(KN0, KN1, KN2, KN3, (itv) + 1)                            \
    float4v c0 = {};                                                          \
    c0 = __builtin_amdgcn_mfma_f32_16x16x32_bf16(KC0, qa0, c0, 0, 0, 0);      \
    c0 = __builtin_amdgcn_mfma_f32_16x16x32_bf16(KC1, qa1, c0, 0, 0, 0);      \
    float4v c1 = {};                                                          \
    c1 = __builtin_amdgcn_mfma_f32_16x16x32_bf16(KC2, qa0, c1, 0, 0, 0);      \
    c1 = __builtin_amdgcn_mfma_f32_16x16x32_bf16(KC3, qa1, c1, 0, 0, 0);      \
    sum += __expf(fmaf(SCALE, c0[0], bv0.x));                                 \
    sum += __expf(fmaf(SCALE, c0[1], bv0.y));                                 \
    sum += __expf(fmaf(SCALE, c0[2], bv0.z));                                 \
    sum += __expf(fmaf(SCALE, c0[3], bv0.w));                                 \
    sum += __expf(fmaf(SCALE, c1[0], bv1.x));                                 \
    sum += __expf(fmaf(SCALE, c1[1], bv1.y));                                 \
    sum += __expf(fmaf(SCALE, c1[2], bv1.z));                                 \
    sum += __expf(fmaf(SCALE, c1[3], bv1.w));                                 \
  }
__global__ void __launch_bounds__(512, 4)
k2_passA(const short* __restrict__ Qb, const short* __restrict__ Kb,
         const float* __restrict__ bias, float* __restrict__ S_part) {
  int lane = threadIdx.x & 63, w = threadIdx.x >> 6;  // w = head
  int lr = lane & 15, lg = lane >> 4;
  int l0 = blockIdx.x * 16;
  int chunk = blockIdx.y;
  int r_base = chunk * CHUNK;
  float sum = 0.f;  // partial for q=lr over this lane's r columns
  const short* qrow = Qb + (l0 + lr) * 512 + 8 * lg;
  short8 qa0 = *reinterpret_cast<const short8*>(qrow + w * 64);
  short8 qa1 = *reinterpret_cast<const short8*>(qrow + w * 64 + 32);
  short8 ka0, ka1, ka2, ka3, kb0, kb1, kb2, kb3;
  PREFK(ka0, ka1, ka2, ka3, 0)
#pragma unroll 1
  for (int it2 = 0; it2 < 8; ++it2) {
    K2_BODY(2 * it2,     ka0, ka1, ka2, ka3, kb0, kb1, kb2, kb3, true)
    K2_BODY(2 * it2 + 1, kb0, kb1, kb2, kb3, ka0, ka1, ka2, ka3, (it2 < 7))
  }
  // reduce across the 4 lg-groups (lanes lr, lr+16, lr+32, lr+48)
  sum += __shfl_xor(sum, 16, 64);
  sum += __shfl_xor(sum, 32, 64);
  if (lane < 16)
    S_part[(chunk * 8 + w) * NL + l0 + lane] = sum;
}

// ---------------- K2b: reduce S partials -> 1/S ------------------------------
__global__ void k2b_reduceS(const float* __restrict__ S_part, float* __restrict__ Sinv) {
  int i = blockIdx.x * blockDim.x + threadIdx.x;  // h*2048 + l
  int h = i >> 11, l = i & 2047;
  float s = 0.f;
#pragma unroll
  for (int c = 0; c < NCHUNK; ++c) s += S_part[(c * 8 + h) * NL + l];
  Sinv[i] = 1.0f / s;
}

// ---------------- K3: pass B — attn_mean + PV partials -----------------------
// Swapped QK, K/bias register prefetch one iter ahead, VT issued at body top,
// RAW s_barrier + explicit lgkmcnt(0) so vmem prefetches survive the barrier.
// P double-buffered in LDS; ONE barrier per 32-col iteration.
#define K3_BODY(itv, cbv, KC0, KC1, KC2, KC3, BC0, BC1,                       \
                KN0, KN1, KN2, KN3, BN0, BN1, PREF)                           \
  {                                                                           \
    int r0 = r_base + (itv) * 32;                                             \
    const short* vbase = VT + (size_t)(w * 64 + lr) * 4096 + r0 + 8 * lg;     \
    short8 vv0 = *reinterpret_cast<const short8*>(vbase);                     \
    short8 vv1 = *reinterpret_cast<const short8*>(vbase + 16 * 4096);         \
    short8 vv2 = *reinterpret_cast<const short8*>(vbase + 32 * 4096);         \
    short8 vv3 = *reinterpret_cast<const short8*>(vbase + 48 * 4096);         \
    if (PREF) {                                                               \
      PREFK(KN0, KN1, KN2, KN3, (itv) + 1)                                    \
      const float* bpn = bias + (size_t)(l0 + lr) * NR + ((itv) + 1) * 32 +   \
                         r_base + 4 * lg;                                     \
      BN0 = *reinterpret_cast<const float4*>(bpn);                            \
      BN1 = *reinterpret_cast<const float4*>(bpn + 16);                       \
    }                                                                         \
    float4v c0 = {};                                                          \
    c0 = __builtin_amdgcn_mfma_f32_16x16x32_bf16(KC0, qa0, c0, 0, 0, 0);      \
    c0 = __builtin_amdgcn_mfma_f32_16x16x32_bf16(KC1, qa1, c0, 0, 0, 0);      \
    float4v c1 = {};                                                          \
    c1 = __builtin_amdgcn_mfma_f32_16x16x32_bf16(KC2, qa0, c1, 0, 0, 0);      \
    c1 = __builtin_amdgcn_mfma_f32_16x16x32_bf16(KC3, qa1, c1, 0, 0, 0);      \
    uint2 pk0, pk1;                                                           \
    pk0.x = cvtpk(__expf(fmaf(SCALE, c0[0], BC0.x)) * sinv,                   \
                  __expf(fmaf(SCALE, c0[1], BC0.y)) * sinv);                  \
    pk0.y = cvtpk(__expf(fmaf(SCALE, c0[2], BC0.z)) * sinv,                   \
                  __expf(fmaf(SCALE, c0[3], BC0.w)) * sinv);                  \
    pk1.x = cvtpk(__expf(fmaf(SCALE, c1[0], BC1.x)) * sinv,                   \
                  __expf(fmaf(SCALE, c1[1], BC1.y)) * sinv);                  \
    pk1.y = cvtpk(__expf(fmaf(SCALE, c1[2], BC1.z)) * sinv,                   \
                  __expf(fmaf(SCALE, c1[3], BC1.w)) * sinv);                  \
    *reinterpret_cast<uint2*>(&P[w][cbv][lr][4 * lg]) = pk0;                  \
    *reinterpret_cast<uint2*>(&P[w][cbv][lr][16 + 4 * lg]) = pk1;             \
    short8 pa = *reinterpret_cast<const short8*>(&P[w][cbv][lr][8 * lg]);     \
    acc[0] = __builtin_amdgcn_mfma_f32_16x16x32_bf16(pa, vv0, acc[0], 0, 0, 0); \
    acc[1] = __builtin_amdgcn_mfma_f32_16x16x32_bf16(pa, vv1, acc[1], 0, 0, 0); \
    acc[2] = __builtin_amdgcn_mfma_f32_16x16x32_bf16(pa, vv2, acc[2], 0, 0, 0); \
    acc[3] = __builtin_amdgcn_mfma_f32_16x16x32_bf16(pa, vv3, acc[3], 0, 0, 0); \
    asm volatile("s_waitcnt lgkmcnt(0)" ::: "memory");                        \
    __builtin_amdgcn_s_barrier();                                             \
    {                                                                         \
      float v = 0.f;                                                          \
      _Pragma("unroll") for (int hh = 0; hh < 8; ++hh)                        \
          v += bf2f(P[hh][cbv][sq][sr]);                                      \
      attn_mean[(size_t)(l0 + sq) * NR + r0 + sr] = v * 0.125f;               \
    }                                                                         \
  }
__global__ void __launch_bounds__(512, 4)
k3_passB(const short* __restrict__ Qb, const short* __restrict__ Kb,
         const short* __restrict__ VT, const float* __restrict__ bias,
         const float* __restrict__ Sinv,
         float* __restrict__ attn_mean, short* __restrict__ ctx_part) {
  __shared__ __align__(16) short P[8][2][16][40];  // [head][buf][q][r(pad40)] 20.5KB
  int t = threadIdx.x;
  int lane = t & 63, w = t >> 6;  // w = head
  int lr = lane & 15, lg = lane >> 4;
  int l0 = blockIdx.x * 16;
  int chunk = blockIdx.y;
  int r_base = chunk * CHUNK;
  float4v acc[4] = {};  // [ds]: ctx[q=4lg+j][d=ds*16+lr], normalized
  float sinv = Sinv[w * NL + l0 + lr];  // per (head, q=lr)
  const short* qrow = Qb + (l0 + lr) * 512 + 8 * lg;
  short8 qa0 = *reinterpret_cast<const short8*>(qrow + w * 64);
  short8 qa1 = *reinterpret_cast<const short8*>(qrow + w * 64 + 32);
  int sq = t >> 5, sr = t & 31;  // mean coords: q=sq, r=sr
  short8 ka0, ka1, ka2, ka3, kb0, kb1, kb2, kb3;
  float4 ba0, ba1, bb0, bb1;
  PREFK(ka0, ka1, ka2, ka3, 0)
  {
    const float* bp = bias + (size_t)(l0 + lr) * NR + r_base + 4 * lg;
    ba0 = *reinterpret_cast<const float4*>(bp);
    ba1 = *reinterpret_cast<const float4*>(bp + 16);
  }
#pragma unroll 1
  for (int it2 = 0; it2 < 8; ++it2) {
    K3_BODY(2 * it2,     0, ka0, ka1, ka2, ka3, ba0, ba1,
            kb0, kb1, kb2, kb3, bb0, bb1, true)
    K3_BODY(2 * it2 + 1, 1, kb0, kb1, kb2, kb3, bb0, bb1,
            ka0, ka1, ka2, ka3, ba0, ba1, (it2 < 7))
  }
#pragma unroll
  for (int ds = 0; ds < 4; ++ds)
#pragma unroll
    for (int j = 0; j < 4; ++j)
      ctx_part[(chunk * NL + l0 + 4 * lg + j) * 512 + w * 64 + ds * 16 + lr] =
          f2bf(acc[ds][j]);
}

// ---------------- K4pre: sum ctx_part chunks ---------------------------------
__global__ void k4pre(const short* __restrict__ ctx_part, short* __restrict__ ctxsum) {
  int i = blockIdx.x * blockDim.x + threadIdx.x;  // 131072 threads, 8 bf16 each
  float sm[8] = {};
#pragma unroll
  for (int c = 0; c < NCHUNK; ++c) {
    short8 v = *reinterpret_cast<const short8*>(ctx_part + (size_t)c * NL * 512 + (size_t)i * 8);
#pragma unroll
    for (int u = 0; u < 8; ++u) sm[u] += bf2f(v[u]);
  }
  short8 o;
#pragma unroll
  for (int u = 0; u < 8; ++u) o[u] = f2bf(sm[u]);
  *reinterpret_cast<short8*>(ctxsum + (size_t)i * 8) = o;
}

// ---------------- K4: ctx @ Wo^T + bo + q, LayerNorm -------------------------
__global__ void k4_out(const short* __restrict__ ctxsum, const short* __restrict__ Wob,
                       const float* __restrict__ q, const float* __restrict__ bo,
                       const float* __restrict__ gamma, const float* __restrict__ beta,
                       float* __restrict__ out) {
  __shared__ float xs[16][512];
  int lane = threadIdx.x & 63, warp = threadIdx.x >> 6;
  int lr = lane & 15, lg = lane >> 4;
  int l0 = blockIdx.x * 16;
  short8 afr[16];
#pragma unroll
  for (int kk = 0; kk < 16; ++kk)
    afr[kk] = *reinterpret_cast<const short8*>(ctxsum + (l0 + lr) * 512 + kk * 32 + 8 * lg);
#pragma unroll 1
  for (int cs = 0; cs < 8; ++cs) {
    int col0 = warp * 128 + cs * 16;
    float4v c = {};
#pragma unroll
    for (int kk = 0; kk < 16; ++kk) {
      const short* bp = Wob + (col0 + lr) * 512 + kk * 32 + 8 * lg;
      short8 b = *reinterpret_cast<const short8*>(bp);
      c = __builtin_amdgcn_mfma_f32_16x16x32_bf16(afr[kk], b, c, 0, 0, 0);
    }
#pragma unroll
    for (int j = 0; j < 4; ++j) {
      int row = l0 + 4 * lg + j, col = col0 + lr;
      xs[4 * lg + j][col] = c[j] + bo[col] + q[row * 512 + col];
    }
  }
  __syncthreads();
  int tid = threadIdx.x;
  int rl = tid >> 4, g = tid & 15;
  float sum = 0.f;
#pragma unroll
  for (int i = 0; i < 32; ++i) sum += xs[rl][g + 16 * i];
  sum += __shfl_xor(sum, 1, 64); sum += __shfl_xor(sum, 2, 64);
  sum += __shfl_xor(sum, 4, 64); sum += __shfl_xor(sum, 8, 64);
  float mu = sum * (1.0f / 512.0f);
  float vs = 0.f;
#pragma unroll
  for (int i = 0; i < 32; ++i) { float d = xs[rl][g + 16 * i] - mu; vs += d * d; }
  vs += __shfl_xor(vs, 1, 64); vs += __shfl_xor(vs, 2, 64);
  vs += __shfl_xor(vs, 4, 64); vs += __shfl_xor(vs, 8, 64);
  float rs = rsqrtf(vs * (1.0f / 512.0f) + LN_EPS);
#pragma unroll
  for (int i = 0; i < 32; ++i) {
    int cc = g + 16 * i;
    out[(l0 + rl) * 512 + cc] = (xs[rl][cc] - mu) * rs * gamma[cc] + beta[cc];
  }
}

extern "C" void kernel_launch(void* const* d_in, const int* in_sizes, int n_in,
                              void* d_out, int out_size, void* d_ws, size_t ws_size,
                              hipStream_t stream) {
  const float* q     = (const float*)d_in[0];
  const float* kv    = (const float*)d_in[1];
  const float* bias  = (const float*)d_in[2];
  const float* Wq    = (const float*)d_in[3];
  const float* Wk    = (const float*)d_in[4];
  const float* Wv    = (const float*)d_in[5];
  const float* Wo    = (const float*)d_in[6];
  const float* bo    = (const float*)d_in[7];
  const float* gamma = (const float*)d_in[8];
  const float* beta  = (const float*)d_in[9];
  float* out = (float*)d_out;
  float* attn_mean = out + (size_t)NL * 512;

  char* ws = (char*)d_ws;
  short* qb       = (short*)(ws + 0);         // 2 MB
  short* kvb      = (short*)(ws + 2097152);   // 4 MB
  short* Wqb      = (short*)(ws + 6291456);   // 512 KB
  short* Wkb      = (short*)(ws + 6815744);
  short* Wvb      = (short*)(ws + 7340032);
  short* Wob      = (short*)(ws + 7864320);
  short* Qb       = (short*)(ws + 8388608);   // 2 MB
  short* Kb       = (short*)(ws + 10485760);  // 4 MB
  short* VT       = (short*)(ws + 14680064);  // 4 MB
  float* S_part   = (float*)(ws + 18874368);  // 512 KB
  float* Sinv     = (float*)(ws + 19398656);  // 64 KB
  short* ctx_part = (short*)(ws + 19464192);  // 16 MB
  short* ctxsum   = (short*)(ws + 36241408);  // 2 MB  (total ~38.2 MB)

  k0_cvt<<<2048, 256, 0, stream>>>(q, kv, Wq, Wk, Wv, Wo, qb, kvb, Wqb, Wkb, Wvb, Wob);
  k1_proj<<<1280, 256, 0, stream>>>(qb, kvb, Wqb, Wkb, Wvb, Qb, Kb, VT);
  k2_passA<<<dim3(128, 8), 512, 0, stream>>>(Qb, Kb, bias, S_part);
  k2b_reduceS<<<64, 256, 0, stream>>>(S_part, Sinv);
  k3_passB<<<dim3(128, 8), 512, 0, stream>>>(Qb, Kb, VT, bias, Sinv, attn_mean, ctx_part);
  k4pre<<<512, 256, 0, stream>>>(ctx_part, ctxsum);
  k4_out<<<128, 256, 0, stream>>>(ctxsum, Wob, q, bo, gamma, beta, out);
}

// Round 11
// 317.663 us; speedup vs baseline: 1.2994x; 1.2994x over previous
//
#include <hip/hip_runtime.h>
#include <hip/hip_bf16.h>
#include <stdint.h>

#define NL 2048
#define NR 4096
#define NCHUNK 8
#define CHUNK (NR / NCHUNK) /* 512 */
#define SCALE 0.125f
#define LN_EPS 1e-5f

typedef __attribute__((ext_vector_type(8))) short short8;  // 8 bf16 in 4 VGPRs
typedef __attribute__((ext_vector_type(4))) float float4v;

static __device__ __forceinline__ short f2bf(float f) {
  union { float f; uint32_t u; } v; v.f = f;
  uint32_t u = v.u;
  uint32_t r = (u + 0x7FFFu + ((u >> 16) & 1u)) >> 16;  // RNE
  return (short)(r & 0xFFFFu);
}
static __device__ __forceinline__ float bf2f(short b) {
  union { uint32_t u; float f; } v; v.u = ((uint32_t)(uint16_t)b) << 16;
  return v.f;
}
// packed f32x2 -> bf16x2 (RNE), lo = a, hi = b
static __device__ __forceinline__ uint32_t cvtpk(float a, float b) {
  uint32_t r;
  asm("v_cvt_pk_bf16_f32 %0, %1, %2" : "=v"(r) : "v"(a), "v"(b));
  return r;
}

// ---------------- K0: fp32 -> bf16 conversions -------------------------------
__global__ void k0_cvt(const float* __restrict__ q, const float* __restrict__ kv,
                       const float* __restrict__ Wq, const float* __restrict__ Wk,
                       const float* __restrict__ Wv, const float* __restrict__ Wo,
                       short* __restrict__ qb, short* __restrict__ kvb,
                       short* __restrict__ Wqb, short* __restrict__ Wkb,
                       short* __restrict__ Wvb, short* __restrict__ Wob) {
  int i = blockIdx.x * blockDim.x + threadIdx.x;
  const float* src; short* dst;
  if (i < 131072)                 { src = q;  dst = qb;  }
  else if ((i -= 131072) < 262144){ src = kv; dst = kvb; }
  else if ((i -= 262144) < 32768) { src = Wq; dst = Wqb; }
  else if ((i -= 32768) < 32768)  { src = Wk; dst = Wkb; }
  else if ((i -= 32768) < 32768)  { src = Wv; dst = Wvb; }
  else { i -= 32768;                src = Wo; dst = Wob; }
  const float4* s4 = reinterpret_cast<const float4*>(src) + (size_t)i * 2;
  float4 a = s4[0], b = s4[1];
  short8 o;
  o[0] = f2bf(a.x); o[1] = f2bf(a.y); o[2] = f2bf(a.z); o[3] = f2bf(a.w);
  o[4] = f2bf(b.x); o[5] = f2bf(b.y); o[6] = f2bf(b.z); o[7] = f2bf(b.w);
  *reinterpret_cast<short8*>(dst + (size_t)i * 8) = o;
}

// ---------------- K1: projections (X @ W^T), 2 M-tiles (32 rows) per wave ----
// Each W fragment feeds 2 MFMAs (halves W traffic, doubles ILP).
// Q: 64 mt x 8 ct = 512 waves; K: 128x8 = 1024; V: 1024. Total 2560 waves.
__global__ void k1_proj(const short* __restrict__ qb, const short* __restrict__ kvb,
                        const short* __restrict__ Wqb, const short* __restrict__ Wkb,
                        const short* __restrict__ Wvb,
                        short* __restrict__ Qb, short* __restrict__ Kb,
                        short* __restrict__ VT) {
  int lane = threadIdx.x & 63, warp = threadIdx.x >> 6;
  int wid = blockIdx.x * 4 + warp;
  int lr = lane & 15, lg = lane >> 4;
  const short *src, *W; short* dst; int mt, ct, mode;
  if (wid < 512)       { src = qb;  W = Wqb; dst = Qb; mt = wid & 63;  ct = wid >> 6; mode = 0; }
  else if (wid < 1536) { int id = wid - 512;  src = kvb; W = Wkb; dst = Kb; mt = id & 127; ct = id >> 7; mode = 0; }
  else                 { int id = wid - 1536; src = kvb; W = Wvb; dst = VT; mt = id & 127; ct = id >> 7; mode = 1; }
  int m0 = mt * 32, c0 = ct * 64;
  float4v acc[2][4] = {};
  const short* arow0 = src + (m0 + lr) * 512 + 8 * lg;
  const short* arow1 = arow0 + 16 * 512;
#pragma unroll
  for (int kk = 0; kk < 16; ++kk) {
    short8 a0 = *reinterpret_cast<const short8*>(arow0 + kk * 32);
    short8 a1 = *reinterpret_cast<const short8*>(arow1 + kk * 32);
#pragma unroll
    for (int cs = 0; cs < 4; ++cs) {
      const short* bp = W + (c0 + cs * 16 + lr) * 512 + kk * 32 + 8 * lg;
      short8 b = *reinterpret_cast<const short8*>(bp);
      acc[0][cs] = __builtin_amdgcn_mfma_f32_16x16x32_bf16(a0, b, acc[0][cs], 0, 0, 0);
      acc[1][cs] = __builtin_amdgcn_mfma_f32_16x16x32_bf16(a1, b, acc[1][cs], 0, 0, 0);
    }
  }
  if (mode == 0) {
#pragma unroll
    for (int t = 0; t < 2; ++t)
#pragma unroll
      for (int cs = 0; cs < 4; ++cs)
#pragma unroll
        for (int j = 0; j < 4; ++j)
          dst[(m0 + t * 16 + 4 * lg + j) * 512 + c0 + cs * 16 + lr] = f2bf(acc[t][cs][j]);
  } else {
#pragma unroll
    for (int t = 0; t < 2; ++t)
#pragma unroll
      for (int cs = 0; cs < 4; ++cs)
#pragma unroll
        for (int j = 0; j < 4; ++j)
          dst[(c0 + cs * 16 + lr) * 4096 + m0 + t * 16 + 4 * lg + j] = f2bf(acc[t][cs][j]);
  }
}

// ---------------- K2: pass A — sum of exp(logit), 2 q-tiles per wave ---------
// Swapped QK: lane holds logits for q=lane&15 (per tile) at 8 r's.
// K fragments shared across both q-tiles. No LDS, no barriers.
__global__ void __launch_bounds__(512, 4)
k2_passA(const short* __restrict__ Qb, const short* __restrict__ Kb,
         const float* __restrict__ bias, float* __restrict__ S_part) {
  int lane = threadIdx.x & 63, w = threadIdx.x >> 6;  // w = head
  int lr = lane & 15, lg = lane >> 4;
  int l0 = blockIdx.x * 32;
  int chunk = blockIdx.y;
  int r_base = chunk * CHUNK;
  float sum0 = 0.f, sum1 = 0.f;
  const short* qrow0 = Qb + (l0 + lr) * 512 + w * 64 + 8 * lg;
  const short* qrow1 = qrow0 + 16 * 512;
  short8 qa00 = *reinterpret_cast<const short8*>(qrow0);
  short8 qa01 = *reinterpret_cast<const short8*>(qrow0 + 32);
  short8 qa10 = *reinterpret_cast<const short8*>(qrow1);
  short8 qa11 = *reinterpret_cast<const short8*>(qrow1 + 32);
#pragma unroll 2
  for (int it = 0; it < 16; ++it) {
    int r0 = r_base + it * 32;
    const short* kp0 = Kb + (size_t)(r0 + lr) * 512 + w * 64 + 8 * lg;
    short8 k0 = *reinterpret_cast<const short8*>(kp0);
    short8 k1 = *reinterpret_cast<const short8*>(kp0 + 32);
    const short* kp1 = kp0 + 16 * 512;
    short8 k2 = *reinterpret_cast<const short8*>(kp1);
    short8 k3 = *reinterpret_cast<const short8*>(kp1 + 32);
    const float* bp0 = bias + (size_t)(l0 + lr) * NR + r0 + 4 * lg;
    float4 b00 = *reinterpret_cast<const float4*>(bp0);
    float4 b01 = *reinterpret_cast<const float4*>(bp0 + 16);
    const float* bp1 = bp0 + 16 * NR;
    float4 b10 = *reinterpret_cast<const float4*>(bp1);
    float4 b11 = *reinterpret_cast<const float4*>(bp1 + 16);
    float4v c00 = {}, c01 = {}, c10 = {}, c11 = {};
    c00 = __builtin_amdgcn_mfma_f32_16x16x32_bf16(k0, qa00, c00, 0, 0, 0);
    c00 = __builtin_amdgcn_mfma_f32_16x16x32_bf16(k1, qa01, c00, 0, 0, 0);
    c01 = __builtin_amdgcn_mfma_f32_16x16x32_bf16(k2, qa00, c01, 0, 0, 0);
    c01 = __builtin_amdgcn_mfma_f32_16x16x32_bf16(k3, qa01, c01, 0, 0, 0);
    c10 = __builtin_amdgcn_mfma_f32_16x16x32_bf16(k0, qa10, c10, 0, 0, 0);
    c10 = __builtin_amdgcn_mfma_f32_16x16x32_bf16(k1, qa11, c10, 0, 0, 0);
    c11 = __builtin_amdgcn_mfma_f32_16x16x32_bf16(k2, qa10, c11, 0, 0, 0);
    c11 = __builtin_amdgcn_mfma_f32_16x16x32_bf16(k3, qa11, c11, 0, 0, 0);
    sum0 += __expf(fmaf(SCALE, c00[0], b00.x)) + __expf(fmaf(SCALE, c00[1], b00.y)) +
            __expf(fmaf(SCALE, c00[2], b00.z)) + __expf(fmaf(SCALE, c00[3], b00.w)) +
            __expf(fmaf(SCALE, c01[0], b01.x)) + __expf(fmaf(SCALE, c01[1], b01.y)) +
            __expf(fmaf(SCALE, c01[2], b01.z)) + __expf(fmaf(SCALE, c01[3], b01.w));
    sum1 += __expf(fmaf(SCALE, c10[0], b10.x)) + __expf(fmaf(SCALE, c10[1], b10.y)) +
            __expf(fmaf(SCALE, c10[2], b10.z)) + __expf(fmaf(SCALE, c10[3], b10.w)) +
            __expf(fmaf(SCALE, c11[0], b11.x)) + __expf(fmaf(SCALE, c11[1], b11.y)) +
            __expf(fmaf(SCALE, c11[2], b11.z)) + __expf(fmaf(SCALE, c11[3], b11.w));
  }
  sum0 += __shfl_xor(sum0, 16, 64); sum0 += __shfl_xor(sum0, 32, 64);
  sum1 += __shfl_xor(sum1, 16, 64); sum1 += __shfl_xor(sum1, 32, 64);
  if (lane < 16) {
    S_part[(chunk * 8 + w) * NL + l0 + lane] = sum0;
    S_part[(chunk * 8 + w) * NL + l0 + 16 + lane] = sum1;
  }
}

// ---------------- K2b: reduce S partials -> 1/S ------------------------------
__global__ void k2b_reduceS(const float* __restrict__ S_part, float* __restrict__ Sinv) {
  int i = blockIdx.x * blockDim.x + threadIdx.x;  // h*2048 + l
  int h = i >> 11, l = i & 2047;
  float s = 0.f;
#pragma unroll
  for (int c = 0; c < NCHUNK; ++c) s += S_part[(c * 8 + h) * NL + l];
  Sinv[i] = 1.0f / s;
}

// ---------------- K3: pass B — attn_mean + PV partials, 2 q-tiles/wave -------
// Swapped QK; K/VT fragments feed both q-tiles. P dbuf [8][2][32][36] (72KB),
// one __syncthreads per 32-col iteration (round-8-verified hazard pattern).
__global__ void __launch_bounds__(512, 4)
k3_passB(const short* __restrict__ Qb, const short* __restrict__ Kb,
         const short* __restrict__ VT, const float* __restrict__ bias,
         const float* __restrict__ Sinv,
         float* __restrict__ attn_mean, short* __restrict__ ctx_part) {
  __shared__ __align__(16) short P[8][2][32][36];  // [head][buf][q(32)][r(pad36)] 72KB
  int t = threadIdx.x;
  int lane = t & 63, w = t >> 6;  // w = head
  int lr = lane & 15, lg = lane >> 4;
  int l0 = blockIdx.x * 32;
  int chunk = blockIdx.y;
  int r_base = chunk * CHUNK;
  float4v acc[2][4] = {};  // [tile][ds]: ctx[q=4lg+j][d=ds*16+lr]
  float sinv0 = Sinv[w * NL + l0 + lr];
  float sinv1 = Sinv[w * NL + l0 + 16 + lr];
  const short* qrow0 = Qb + (l0 + lr) * 512 + w * 64 + 8 * lg;
  const short* qrow1 = qrow0 + 16 * 512;
  short8 qa00 = *reinterpret_cast<const short8*>(qrow0);
  short8 qa01 = *reinterpret_cast<const short8*>(qrow0 + 32);
  short8 qa10 = *reinterpret_cast<const short8*>(qrow1);
  short8 qa11 = *reinterpret_cast<const short8*>(qrow1 + 32);
  int sq = t >> 4, sc = (t & 15) * 2;  // mean coords: row 0..31, col base (2 cols)
#pragma unroll 1
  for (int it = 0; it < 16; ++it) {
    int cb = it & 1;
    int r0 = r_base + it * 32;
    // shared operand loads (feed both q-tiles)
    const short* kp0 = Kb + (size_t)(r0 + lr) * 512 + w * 64 + 8 * lg;
    short8 k0 = *reinterpret_cast<const short8*>(kp0);
    short8 k1 = *reinterpret_cast<const short8*>(kp0 + 32);
    const short* kp1 = kp0 + 16 * 512;
    short8 k2 = *reinterpret_cast<const short8*>(kp1);
    short8 k3 = *reinterpret_cast<const short8*>(kp1 + 32);
    const short* vbase = VT + (size_t)(w * 64 + lr) * 4096 + r0 + 8 * lg;
    short8 vv0 = *reinterpret_cast<const short8*>(vbase);
    short8 vv1 = *reinterpret_cast<const short8*>(vbase + 16 * 4096);
    short8 vv2 = *reinterpret_cast<const short8*>(vbase + 32 * 4096);
    short8 vv3 = *reinterpret_cast<const short8*>(vbase + 48 * 4096);
    const float* bp0 = bias + (size_t)(l0 + lr) * NR + r0 + 4 * lg;
    float4 b00 = *reinterpret_cast<const float4*>(bp0);
    float4 b01 = *reinterpret_cast<const float4*>(bp0 + 16);
    const float* bp1 = bp0 + 16 * NR;
    float4 b10 = *reinterpret_cast<const float4*>(bp1);
    float4 b11 = *reinterpret_cast<const float4*>(bp1 + 16);
    // QK^T (swapped) for both tiles
    float4v c00 = {}, c01 = {}, c10 = {}, c11 = {};
    c00 = __builtin_amdgcn_mfma_f32_16x16x32_bf16(k0, qa00, c00, 0, 0, 0);
    c00 = __builtin_amdgcn_mfma_f32_16x16x32_bf16(k1, qa01, c00, 0, 0, 0);
    c01 = __builtin_amdgcn_mfma_f32_16x16x32_bf16(k2, qa00, c01, 0, 0, 0);
    c01 = __builtin_amdgcn_mfma_f32_16x16x32_bf16(k3, qa01, c01, 0, 0, 0);
    c10 = __builtin_amdgcn_mfma_f32_16x16x32_bf16(k0, qa10, c10, 0, 0, 0);
    c10 = __builtin_amdgcn_mfma_f32_16x16x32_bf16(k1, qa11, c10, 0, 0, 0);
    c11 = __builtin_amdgcn_mfma_f32_16x16x32_bf16(k2, qa10, c11, 0, 0, 0);
    c11 = __builtin_amdgcn_mfma_f32_16x16x32_bf16(k3, qa11, c11, 0, 0, 0);
    // normalized P -> packed bf16 -> LDS
    uint2 pk;
    pk.x = cvtpk(__expf(fmaf(SCALE, c00[0], b00.x)) * sinv0,
                 __expf(fmaf(SCALE, c00[1], b00.y)) * sinv0);
    pk.y = cvtpk(__expf(fmaf(SCALE, c00[2], b00.z)) * sinv0,
                 __expf(fmaf(SCALE, c00[3], b00.w)) * sinv0);
    *reinterpret_cast<uint2*>(&P[w][cb][lr][4 * lg]) = pk;
    pk.x = cvtpk(__expf(fmaf(SCALE, c01[0], b01.x)) * sinv0,
                 __expf(fmaf(SCALE, c01[1], b01.y)) * sinv0);
    pk.y = cvtpk(__expf(fmaf(SCALE, c01[2], b01.z)) * sinv0,
                 __expf(fmaf(SCALE, c01[3], b01.w)) * sinv0);
    *reinterpret_cast<uint2*>(&P[w][cb][lr][16 + 4 * lg]) = pk;
    pk.x = cvtpk(__expf(fmaf(SCALE, c10[0], b10.x)) * sinv1,
                 __expf(fmaf(SCALE, c10[1], b10.y)) * sinv1);
    pk.y = cvtpk(__expf(fmaf(SCALE, c10[2], b10.z)) * sinv1,
                 __expf(fmaf(SCALE, c10[3], b10.w)) * sinv1);
    *reinterpret_cast<uint2*>(&P[w][cb][16 + lr][4 * lg]) = pk;
    pk.x = cvtpk(__expf(fmaf(SCALE, c11[0], b11.x)) * sinv1,
                 __expf(fmaf(SCALE, c11[1], b11.y)) * sinv1);
    pk.y = cvtpk(__expf(fmaf(SCALE, c11[2], b11.z)) * sinv1,
                 __expf(fmaf(SCALE, c11[3], b11.w)) * sinv1);
    *reinterpret_cast<uint2*>(&P[w][cb][16 + lr][16 + 4 * lg]) = pk;
    // PV for both tiles (VT fragments reused)
    short8 pa0 = *reinterpret_cast<const short8*>(&P[w][cb][lr][8 * lg]);
    short8 pa1 = *reinterpret_cast<const short8*>(&P[w][cb][16 + lr][8 * lg]);
    acc[0][0] = __builtin_amdgcn_mfma_f32_16x16x32_bf16(pa0, vv0, acc[0][0], 0, 0, 0);
    acc[0][1] = __builtin_amdgcn_mfma_f32_16x16x32_bf16(pa0, vv1, acc[0][1], 0, 0, 0);
    acc[0][2] = __builtin_amdgcn_mfma_f32_16x16x32_bf16(pa0, vv2, acc[0][2], 0, 0, 0);
    acc[0][3] = __builtin_amdgcn_mfma_f32_16x16x32_bf16(pa0, vv3, acc[0][3], 0, 0, 0);
    acc[1][0] = __builtin_amdgcn_mfma_f32_16x16x32_bf16(pa1, vv0, acc[1][0], 0, 0, 0);
    acc[1][1] = __builtin_amdgcn_mfma_f32_16x16x32_bf16(pa1, vv1, acc[1][1], 0, 0, 0);
    acc[1][2] = __builtin_amdgcn_mfma_f32_16x16x32_bf16(pa1, vv2, acc[1][2], 0, 0, 0);
    acc[1][3] = __builtin_amdgcn_mfma_f32_16x16x32_bf16(pa1, vv3, acc[1][3], 0, 0, 0);
    __syncthreads();  // P[*][cb] complete for all heads
    // attn_mean over this iter's 32x32 tile: thread -> (row sq, 2 cols at sc)
    {
      float v0 = 0.f, v1 = 0.f;
#pragma unroll
      for (int hh = 0; hh < 8; ++hh) {
        uint32_t p2 = *reinterpret_cast<const uint32_t*>(&P[hh][cb][sq][sc]);
        v0 += bf2f((short)(p2 & 0xFFFFu));
        v1 += bf2f((short)(p2 >> 16));
      }
      float2 o; o.x = v0 * 0.125f; o.y = v1 * 0.125f;
      *reinterpret_cast<float2*>(&attn_mean[(size_t)(l0 + sq) * NR + r0 + sc]) = o;
    }
    // next iter writes P[cb^1]; P[cb] re-written at it+2, after barrier(it+1)
  }
#pragma unroll
  for (int tt = 0; tt < 2; ++tt)
#pragma unroll
    for (int ds = 0; ds < 4; ++ds)
#pragma unroll
      for (int j = 0; j < 4; ++j)
        ctx_part[(chunk * NL + l0 + tt * 16 + 4 * lg + j) * 512 + w * 64 + ds * 16 + lr] =
            f2bf(acc[tt][ds][j]);
}

// ---------------- K4pre: sum ctx_part chunks ---------------------------------
__global__ void k4pre(const short* __restrict__ ctx_part, short* __restrict__ ctxsum) {
  int i = blockIdx.x * blockDim.x + threadIdx.x;  // 131072 threads, 8 bf16 each
  float sm[8] = {};
#pragma unroll
  for (int c = 0; c < NCHUNK; ++c) {
    short8 v = *reinterpret_cast<const short8*>(ctx_part + (size_t)c * NL * 512 + (size_t)i * 8);
#pragma unroll
    for (int u = 0; u < 8; ++u) sm[u] += bf2f(v[u]);
  }
  short8 o;
#pragma unroll
  for (int u = 0; u < 8; ++u) o[u] = f2bf(sm[u]);
  *reinterpret_cast<short8*>(ctxsum + (size_t)i * 8) = o;
}

// ---------------- K4: ctx @ Wo^T + bo + q, LayerNorm -------------------------
__global__ void k4_out(const short* __restrict__ ctxsum, const short* __restrict__ Wob,
                       const float* __restrict__ q, const float* __restrict__ bo,
                       const float* __restrict__ gamma, const float* __restrict__ beta,
                       float* __restrict__ out) {
  __shared__ float xs[16][512];
  int lane = threadIdx.x & 63, warp = threadIdx.x >> 6;
  int lr = lane & 15, lg = lane >> 4;
  int l0 = blockIdx.x * 16;
  short8 afr[16];
#pragma unroll
  for (int kk = 0; kk < 16; ++kk)
    afr[kk] = *reinterpret_cast<const short8*>(ctxsum + (l0 + lr) * 512 + kk * 32 + 8 * lg);
#pragma unroll 1
  for (int cs = 0; cs < 8; ++cs) {
    int col0 = warp * 128 + cs * 16;
    float4v c = {};
#pragma unroll
    for (int kk = 0; kk < 16; ++kk) {
      const short* bp = Wob + (col0 + lr) * 512 + kk * 32 + 8 * lg;
      short8 b = *reinterpret_cast<const short8*>(bp);
      c = __builtin_amdgcn_mfma_f32_16x16x32_bf16(afr[kk], b, c, 0, 0, 0);
    }
#pragma unroll
    for (int j = 0; j < 4; ++j) {
      int row = l0 + 4 * lg + j, col = col0 + lr;
      xs[4 * lg + j][col] = c[j] + bo[col] + q[row * 512 + col];
    }
  }
  __syncthreads();
  int tid = threadIdx.x;
  int rl = tid >> 4, g = tid & 15;
  float sum = 0.f;
#pragma unroll
  for (int i = 0; i < 32; ++i) sum += xs[rl][g + 16 * i];
  sum += __shfl_xor(sum, 1, 64); sum += __shfl_xor(sum, 2, 64);
  sum += __shfl_xor(sum, 4, 64); sum += __shfl_xor(sum, 8, 64);
  float mu = sum * (1.0f / 512.0f);
  float vs = 0.f;
#pragma unroll
  for (int i = 0; i < 32; ++i) { float d = xs[rl][g + 16 * i] - mu; vs += d * d; }
  vs += __shfl_xor(vs, 1, 64); vs += __shfl_xor(vs, 2, 64);
  vs += __shfl_xor(vs, 4, 64); vs += __shfl_xor(vs, 8, 64);
  float rs = rsqrtf(vs * (1.0f / 512.0f) + LN_EPS);
#pragma unroll
  for (int i = 0; i < 32; ++i) {
    int cc = g + 16 * i;
    out[(l0 + rl) * 512 + cc] = (xs[rl][cc] - mu) * rs * gamma[cc] + beta[cc];
  }
}

extern "C" void kernel_launch(void* const* d_in, const int* in_sizes, int n_in,
                              void* d_out, int out_size, void* d_ws, size_t ws_size,
                              hipStream_t stream) {
  const float* q     = (const float*)d_in[0];
  const float* kv    = (const float*)d_in[1];
  const float* bias  = (const float*)d_in[2];
  const float* Wq    = (const float*)d_in[3];
  const float* Wk    = (const float*)d_in[4];
  const float* Wv    = (const float*)d_in[5];
  const float* Wo    = (const float*)d_in[6];
  const float* bo    = (const float*)d_in[7];
  const float* gamma = (const float*)d_in[8];
  const float* beta  = (const float*)d_in[9];
  float* out = (float*)d_out;
  float* attn_mean = out + (size_t)NL * 512;

  char* ws = (char*)d_ws;
  short* qb       = (short*)(ws + 0);         // 2 MB
  short* kvb      = (short*)(ws + 2097152);   // 4 MB
  short* Wqb      = (short*)(ws + 6291456);   // 512 KB
  short* Wkb      = (short*)(ws + 6815744);
  short* Wvb      = (short*)(ws + 7340032);
  short* Wob      = (short*)(ws + 7864320);
  short* Qb       = (short*)(ws + 8388608);   // 2 MB
  short* Kb       = (short*)(ws + 10485760);  // 4 MB
  short* VT       = (short*)(ws + 14680064);  // 4 MB
  float* S_part   = (float*)(ws + 18874368);  // 512 KB
  float* Sinv     = (float*)(ws + 19398656);  // 64 KB
  short* ctx_part = (short*)(ws + 19464192);  // 16 MB
  short* ctxsum   = (short*)(ws + 36241408);  // 2 MB  (total ~38.2 MB)

  k0_cvt<<<2048, 256, 0, stream>>>(q, kv, Wq, Wk, Wv, Wo, qb, kvb, Wqb, Wkb, Wvb, Wob);
  k1_proj<<<640, 256, 0, stream>>>(qb, kvb, Wqb, Wkb, Wvb, Qb, Kb, VT);
  k2_passA<<<dim3(64, 8), 512, 0, stream>>>(Qb, Kb, bias, S_part);
  k2b_reduceS<<<64, 256, 0, stream>>>(S_part, Sinv);
  k3_passB<<<dim3(64, 8), 512, 0, stream>>>(Qb, Kb, VT, bias, Sinv, attn_mean, ctx_part);
  k4pre<<<512, 256, 0, stream>>>(ctx_part, ctxsum);
  k4_out<<<128, 256, 0, stream>>>(ctxsum, Wob, q, bo, gamma, beta, out);
}